// Round 2
// baseline (334.591 us; speedup 1.0000x reference)
//
#include <hip/hip_runtime.h>
#include <math.h>

#define N_EDGES   1000000
#define THR_LO    0.6f
#define THR_HI    0.8f
#define LOG_CLAMP -100.0f

// d_ws layout: float acc[4] (sim_sum, disim_sum, n_sim, n_disim), uint done.
// Zeroed by hipMemsetAsync each launch.
__global__ void __launch_bounds__(256)
edge_loss_kernel(const int2* __restrict__ edges,
                 const float* __restrict__ probas,
                 const float4* __restrict__ feats,   // [N_NODES][16] float4 rows
                 float* __restrict__ acc,
                 unsigned int* __restrict__ done,
                 float* __restrict__ out,
                 int nblocks) {
    const int e    = blockIdx.x * blockDim.x + threadIdx.x;
    const int lane = threadIdx.x & 63;
    const int wave = threadIdx.x >> 6;

    // ---- mask phase: 1 edge per lane, coalesced ----
    const bool in = (e < N_EDGES);
    int2 ij = make_int2(0, 0);
    if (in) ij = edges[e];
    float pi = probas[ij.x];
    float pj = probas[ij.y];
    bool msim = in && (pi >= THR_HI) && (pj >= THR_HI);
    bool mdis = in && (((pi >= THR_HI) && (pj < THR_LO)) ||
                       ((pj >= THR_HI) && (pi < THR_LO)));

    unsigned long long balsim = __ballot(msim);
    unsigned long long baldis = __ballot(mdis);
    unsigned long long m      = balsim | baldis;   // sim/disim mutually exclusive

    float simacc = 0.f, disacc = 0.f, ns = 0.f, nd = 0.f;
    if (lane == 0) {
        ns = (float)__popcll(balsim);
        nd = (float)__popcll(baldis);
    }

    // ---- cooperative phase: 2 active edges per pass ----
    // lanes 0-31 -> edge a, lanes 32-63 -> edge b
    // within each half: lanes [0,16) load row i, [16,32) load row j (coalesced 256B rows)
    const int half     = lane >> 5;
    const int sub      = lane & 15;
    const int whichrow = (lane >> 4) & 1;

    while (m) {
        int l0 = __ffsll(m) - 1; m &= m - 1;
        int l1 = -1;
        if (m) { l1 = __ffsll(m) - 1; m &= m - 1; }

        bool have = (half == 0) || (l1 >= 0);
        int  src  = (half && l1 >= 0) ? l1 : l0;
        int  bi   = __shfl(ij.x, src);
        int  bj   = __shfl(ij.y, src);
        int  bsim = __shfl((int)msim, src);

        float4 v = make_float4(0.f, 0.f, 0.f, 0.f);
        if (have) {
            const float4* row = feats + (size_t)(whichrow ? bj : bi) * 16;
            v = row[sub];
        }
        // partner row's float4 (lane^16 swaps row i <-> row j within each half)
        float dx = v.x - __shfl_xor(v.x, 16);
        float dy = v.y - __shfl_xor(v.y, 16);
        float dz = v.z - __shfl_xor(v.z, 16);
        float dw = v.w - __shfl_xor(v.w, 16);
        float s = dx * dx + dy * dy + dz * dz + dw * dw;
        // reduce the 16 float4-chunks of this edge-half
        s += __shfl_xor(s, 8);
        s += __shfl_xor(s, 4);
        s += __shfl_xor(s, 2);
        s += __shfl_xor(s, 1);

        if (((lane & 31) == 0) && have) {
            float d = sqrtf(s);
            if (bsim) {
                simacc += fminf(d, 100.0f);     // -max(log(exp(-d)),-100)
            } else {
                float p = expf(-d);
                disacc += -fmaxf(log1pf(-p), LOG_CLAMP);
            }
        }
    }

    // ---- block reduction ----
    #pragma unroll
    for (int off = 32; off > 0; off >>= 1) {
        simacc += __shfl_down(simacc, off);
        disacc += __shfl_down(disacc, off);
        ns     += __shfl_down(ns,     off);
        nd     += __shfl_down(nd,     off);
    }
    __shared__ float lds[4][4];
    if (lane == 0) {
        lds[wave][0] = simacc; lds[wave][1] = disacc;
        lds[wave][2] = ns;     lds[wave][3] = nd;
    }
    __syncthreads();
    if (threadIdx.x == 0) {
        float a = 0.f, b = 0.f, c = 0.f, d4 = 0.f;
        #pragma unroll
        for (int w = 0; w < 4; ++w) {
            a += lds[w][0]; b += lds[w][1]; c += lds[w][2]; d4 += lds[w][3];
        }
        atomicAdd(&acc[0], a);
        atomicAdd(&acc[1], b);
        atomicAdd(&acc[2], c);
        atomicAdd(&acc[3], d4);
        __threadfence();
        unsigned int ret = atomicAdd(done, 1u);
        if (ret == (unsigned int)nblocks - 1) {
            // last block: all other blocks' acc atomics are visible (fenced)
            float sim_sum   = atomicAdd(&acc[0], 0.f);
            float disim_sum = atomicAdd(&acc[1], 0.f);
            float n_sim     = atomicAdd(&acc[2], 0.f);
            float n_disim   = atomicAdd(&acc[3], 0.f);
            float total = n_sim + n_disim;
            out[0] = (sim_sum * (n_disim / total) +
                      disim_sum * (n_sim / total)) / total;
        }
    }
}

extern "C" void kernel_launch(void* const* d_in, const int* in_sizes, int n_in,
                              void* d_out, int out_size, void* d_ws, size_t ws_size,
                              hipStream_t stream) {
    const int*   edges  = (const int*)d_in[0];    // (N_EDGES, 2) int32
    const float* probas = (const float*)d_in[1];  // (N_NODES,)
    const float* feats  = (const float*)d_in[2];  // (N_NODES, 64)
    float*        acc  = (float*)d_ws;
    unsigned int* done = (unsigned int*)((char*)d_ws + 4 * sizeof(float));

    hipMemsetAsync(d_ws, 0, 32, stream);

    const int block  = 256;
    const int blocks = (N_EDGES + block - 1) / block;   // 3907, one edge per lane
    edge_loss_kernel<<<blocks, block, 0, stream>>>(
        (const int2*)edges, probas, (const float4*)feats,
        acc, done, (float*)d_out, blocks);
}

// Round 3
// 310.241 us; speedup vs baseline: 1.0785x; 1.0785x over previous
//
#include <hip/hip_runtime.h>
#include <math.h>

#define N_EDGES   1000000
#define THR_LO    0.6f
#define THR_HI    0.8f
#define LOG_CLAMP -100.0f

// d_ws layout:
//   [0]  float sim_sum
//   [1]  float disim_sum
//   [2]  uint  n_sim
//   [3]  uint  n_disim
//   [4]  uint  compact_count
//   [5]  uint  done
//   [6,7] pad
//   byte 32+: int2 compacted[N_EDGES]  (x = i | sim<<31, y = j)
#define WS_HDR_BYTES 32

// ---------------- Phase 1: mask + compact ----------------
__global__ void __launch_bounds__(512)
mask_compact_kernel(const int2* __restrict__ edges,
                    const float* __restrict__ probas,
                    unsigned int* __restrict__ hdr,   // ws header as uints
                    int2* __restrict__ cedges) {
    const int e    = blockIdx.x * blockDim.x + threadIdx.x;
    const int lane = threadIdx.x & 63;
    const int wave = threadIdx.x >> 6;

    const bool in = (e < N_EDGES);
    int2 ij = make_int2(0, 0);
    if (in) ij = edges[e];
    float pi = probas[ij.x];
    float pj = probas[ij.y];
    bool msim = in && (pi >= THR_HI) && (pj >= THR_HI);
    bool mdis = in && (((pi >= THR_HI) && (pj < THR_LO)) ||
                       ((pj >= THR_HI) && (pi < THR_LO)));
    bool act  = msim || mdis;     // mutually exclusive in value space

    unsigned long long balsim = __ballot(msim);
    unsigned long long baldis = __ballot(mdis);
    unsigned long long balact = balsim | baldis;

    int nact = __popcll(balact);
    int prefix = __popcll(balact & ((1ULL << lane) - 1ULL));

    // block-level aggregation of the three counters
    __shared__ unsigned int blk_cnt;     // active
    __shared__ unsigned int blk_sim;
    __shared__ unsigned int blk_dis;
    __shared__ unsigned int wave_base[8];
    __shared__ unsigned int blk_base;
    if (threadIdx.x == 0) { blk_cnt = 0u; blk_sim = 0u; blk_dis = 0u; }
    __syncthreads();
    if (lane == 0) {
        wave_base[wave] = atomicAdd(&blk_cnt, (unsigned int)nact);
        atomicAdd(&blk_sim, (unsigned int)__popcll(balsim));
        atomicAdd(&blk_dis, (unsigned int)__popcll(baldis));
    }
    __syncthreads();
    if (threadIdx.x == 0) {
        blk_base = atomicAdd(&hdr[4], blk_cnt);
        atomicAdd(&hdr[2], blk_sim);
        atomicAdd(&hdr[3], blk_dis);
    }
    __syncthreads();

    if (act) {
        unsigned int pos = blk_base + wave_base[wave] + (unsigned int)prefix;
        cedges[pos] = make_int2(ij.x | (msim ? (int)0x80000000 : 0), ij.y);
    }
}

// ---------------- Phase 2: row gathers + loss ----------------
__global__ void __launch_bounds__(256)
loss_kernel(const float4* __restrict__ feats,       // [N_NODES][16]
            const int2* __restrict__ cedges,
            unsigned int* __restrict__ hdr,
            float* __restrict__ out,
            int nblocks) {
    const int lane = threadIdx.x & 63;
    const int wave = threadIdx.x >> 6;
    const int sub  = threadIdx.x & 3;

    const int count   = (int)hdr[4];
    const int gid     = (blockIdx.x * blockDim.x + threadIdx.x) >> 2;
    const int ngroups = (gridDim.x * blockDim.x) >> 2;

    float simacc = 0.f, disacc = 0.f;

    for (int g = gid; g < count; g += ngroups) {
        int2 e = cedges[g];
        int sim = ((unsigned int)e.x) >> 31;
        int i = e.x & 0x7FFFFFFF;
        int j = e.y;
        const float4* ri = feats + (size_t)i * 16;
        const float4* rj = feats + (size_t)j * 16;

        // 8 independent loads per lane; each group-of-4 covers 4x64B lines/row
        float4 a0 = ri[sub +  0], b0 = rj[sub +  0];
        float4 a1 = ri[sub +  4], b1 = rj[sub +  4];
        float4 a2 = ri[sub +  8], b2 = rj[sub +  8];
        float4 a3 = ri[sub + 12], b3 = rj[sub + 12];

        float s = 0.f;
        float dx, dy, dz, dw;
        dx = a0.x - b0.x; dy = a0.y - b0.y; dz = a0.z - b0.z; dw = a0.w - b0.w;
        s += dx*dx + dy*dy + dz*dz + dw*dw;
        dx = a1.x - b1.x; dy = a1.y - b1.y; dz = a1.z - b1.z; dw = a1.w - b1.w;
        s += dx*dx + dy*dy + dz*dz + dw*dw;
        dx = a2.x - b2.x; dy = a2.y - b2.y; dz = a2.z - b2.z; dw = a2.w - b2.w;
        s += dx*dx + dy*dy + dz*dz + dw*dw;
        dx = a3.x - b3.x; dy = a3.y - b3.y; dz = a3.z - b3.z; dw = a3.w - b3.w;
        s += dx*dx + dy*dy + dz*dz + dw*dw;

        s += __shfl_xor(s, 1);
        s += __shfl_xor(s, 2);

        if (sub == 0) {
            float d = sqrtf(s);
            if (sim) {
                simacc += fminf(d, 100.0f);          // -max(log(exp(-d)),-100)
            } else {
                float p = expf(-d);
                disacc += -fmaxf(log1pf(-p), LOG_CLAMP);
            }
        }
    }

    // block reduction
    #pragma unroll
    for (int off = 32; off > 0; off >>= 1) {
        simacc += __shfl_down(simacc, off);
        disacc += __shfl_down(disacc, off);
    }
    __shared__ float lds[4][2];
    if (lane == 0) { lds[wave][0] = simacc; lds[wave][1] = disacc; }
    __syncthreads();
    if (threadIdx.x == 0) {
        float a = 0.f, b = 0.f;
        #pragma unroll
        for (int w = 0; w < 4; ++w) { a += lds[w][0]; b += lds[w][1]; }
        float* facc = (float*)hdr;
        atomicAdd(&facc[0], a);
        atomicAdd(&facc[1], b);
        __threadfence();
        unsigned int ret = atomicAdd(&hdr[5], 1u);
        if (ret == (unsigned int)nblocks - 1) {
            float sim_sum   = atomicAdd(&facc[0], 0.f);
            float disim_sum = atomicAdd(&facc[1], 0.f);
            float n_sim   = (float)hdr[2];
            float n_disim = (float)hdr[3];
            float total = n_sim + n_disim;
            out[0] = (sim_sum * (n_disim / total) +
                      disim_sum * (n_sim / total)) / total;
        }
    }
}

// ---------------- Fallback (R1 kernel) if ws too small ----------------
__global__ void __launch_bounds__(256)
edge_loss_fallback(const int2* __restrict__ edges,
                   const float* __restrict__ probas,
                   const float4* __restrict__ feats,
                   float* __restrict__ acc) {
    int tid    = blockIdx.x * blockDim.x + threadIdx.x;
    int stride = gridDim.x * blockDim.x;
    float sim = 0.f, disim = 0.f, ns = 0.f, nd = 0.f;
    for (int e = tid; e < N_EDGES; e += stride) {
        int2 ij = edges[e];
        float pi = probas[ij.x];
        float pj = probas[ij.y];
        bool msim = (pi >= THR_HI) & (pj >= THR_HI);
        bool mdis = ((pi >= THR_HI) & (pj < THR_LO)) |
                    ((pj >= THR_HI) & (pi < THR_LO));
        if (msim | mdis) {
            const float4* fi = feats + (size_t)ij.x * 16;
            const float4* fj = feats + (size_t)ij.y * 16;
            float s = 0.f;
            #pragma unroll
            for (int k = 0; k < 16; ++k) {
                float4 a = fi[k], b = fj[k];
                float dx = a.x - b.x, dy = a.y - b.y;
                float dz = a.z - b.z, dw = a.w - b.w;
                s += dx*dx + dy*dy + dz*dz + dw*dw;
            }
            float d = sqrtf(s);
            if (msim) { sim += fminf(d, 100.0f); ns += 1.0f; }
            if (mdis) {
                float p = expf(-d);
                disim += -fmaxf(log1pf(-p), LOG_CLAMP);
                nd += 1.0f;
            }
        }
    }
    #pragma unroll
    for (int off = 32; off > 0; off >>= 1) {
        sim += __shfl_down(sim, off); disim += __shfl_down(disim, off);
        ns  += __shfl_down(ns,  off); nd    += __shfl_down(nd,    off);
    }
    __shared__ float lds[4][4];
    int lane = threadIdx.x & 63, wave = threadIdx.x >> 6;
    if (lane == 0) { lds[wave][0]=sim; lds[wave][1]=disim; lds[wave][2]=ns; lds[wave][3]=nd; }
    __syncthreads();
    if (threadIdx.x == 0) {
        float a=0,b=0,c=0,d4=0;
        for (int w = 0; w < 4; ++w) { a+=lds[w][0]; b+=lds[w][1]; c+=lds[w][2]; d4+=lds[w][3]; }
        atomicAdd(&acc[0],a); atomicAdd(&acc[1],b); atomicAdd(&acc[2],c); atomicAdd(&acc[3],d4);
    }
}

__global__ void finalize_fallback(const float* __restrict__ acc, float* __restrict__ out) {
    float total = acc[2] + acc[3];
    out[0] = (acc[0] * (acc[3] / total) + acc[1] * (acc[2] / total)) / total;
}

extern "C" void kernel_launch(void* const* d_in, const int* in_sizes, int n_in,
                              void* d_out, int out_size, void* d_ws, size_t ws_size,
                              hipStream_t stream) {
    const int*   edges  = (const int*)d_in[0];    // (N_EDGES, 2) int32
    const float* probas = (const float*)d_in[1];  // (N_NODES,)
    const float* feats  = (const float*)d_in[2];  // (N_NODES, 64)

    if (ws_size >= WS_HDR_BYTES + (size_t)N_EDGES * sizeof(int2)) {
        unsigned int* hdr = (unsigned int*)d_ws;
        int2* cedges = (int2*)((char*)d_ws + WS_HDR_BYTES);

        hipMemsetAsync(d_ws, 0, WS_HDR_BYTES, stream);

        const int b1 = 512;
        const int g1 = (N_EDGES + b1 - 1) / b1;     // 1954 blocks
        mask_compact_kernel<<<g1, b1, 0, stream>>>(
            (const int2*)edges, probas, hdr, cedges);

        const int b2 = 256;
        const int g2 = 4096;                         // 1.05M lanes, 262K groups
        loss_kernel<<<g2, b2, 0, stream>>>(
            (const float4*)feats, cedges, hdr, (float*)d_out, g2);
    } else {
        float* acc = (float*)d_ws;
        hipMemsetAsync(acc, 0, 4 * sizeof(float), stream);
        edge_loss_fallback<<<2048, 256, 0, stream>>>(
            (const int2*)edges, probas, (const float4*)feats, acc);
        finalize_fallback<<<1, 1, 0, stream>>>(acc, (float*)d_out);
    }
}

// Round 4
// 107.049 us; speedup vs baseline: 3.1256x; 2.8981x over previous
//
#include <hip/hip_runtime.h>
#include <math.h>

#define N_EDGES   1000000
#define THR_LO    0.6f
#define THR_HI    0.8f
#define LOG_CLAMP -100.0f

#define NBLOCKS   2048
#define BLOCK     256

// d_ws: float4 part[NBLOCKS]  (x=sim_sum, y=disim_sum, z=n_sim, w=n_disim)
// Every block writes its slot unconditionally -> no zero-init needed.

__global__ void __launch_bounds__(BLOCK)
edge_loss_kernel(const int2* __restrict__ edges,
                 const float* __restrict__ probas,
                 const float4* __restrict__ feats,   // [N_NODES][16] float4
                 float4* __restrict__ part) {
    int tid    = blockIdx.x * blockDim.x + threadIdx.x;
    int stride = gridDim.x * blockDim.x;

    float sim = 0.f, disim = 0.f, ns = 0.f, nd = 0.f;

    for (int e = tid; e < N_EDGES; e += stride) {
        int2 ij = edges[e];
        float pi = probas[ij.x];
        float pj = probas[ij.y];
        bool msim = (pi >= THR_HI) & (pj >= THR_HI);
        bool mdis = ((pi >= THR_HI) & (pj < THR_LO)) |
                    ((pj >= THR_HI) & (pi < THR_LO));
        if (msim | mdis) {
            const float4* fi = feats + (size_t)ij.x * 16;
            const float4* fj = feats + (size_t)ij.y * 16;
            float s = 0.f;
            #pragma unroll
            for (int k = 0; k < 16; ++k) {
                float4 a = fi[k];
                float4 b = fj[k];
                float dx = a.x - b.x, dy = a.y - b.y;
                float dz = a.z - b.z, dw = a.w - b.w;
                s += dx * dx + dy * dy + dz * dz + dw * dw;
            }
            float d = sqrtf(s);
            if (msim) {
                sim += fminf(d, 100.0f);   // -max(log(exp(-d)),-100) == min(d,100)
                ns  += 1.0f;
            }
            if (mdis) {
                float p = expf(-d);
                disim += -fmaxf(log1pf(-p), LOG_CLAMP);
                nd    += 1.0f;
            }
        }
    }

    // wave-64 shuffle reduction
    #pragma unroll
    for (int off = 32; off > 0; off >>= 1) {
        sim   += __shfl_down(sim,   off);
        disim += __shfl_down(disim, off);
        ns    += __shfl_down(ns,    off);
        nd    += __shfl_down(nd,    off);
    }

    __shared__ float lds[4][4];
    int lane = threadIdx.x & 63;
    int wave = threadIdx.x >> 6;
    if (lane == 0) {
        lds[wave][0] = sim;
        lds[wave][1] = disim;
        lds[wave][2] = ns;
        lds[wave][3] = nd;
    }
    __syncthreads();
    if (threadIdx.x == 0) {
        float a = 0.f, b = 0.f, c = 0.f, d4 = 0.f;
        #pragma unroll
        for (int w = 0; w < 4; ++w) {
            a  += lds[w][0];
            b  += lds[w][1];
            c  += lds[w][2];
            d4 += lds[w][3];
        }
        part[blockIdx.x] = make_float4(a, b, c, d4);   // plain store, no contention
    }
}

__global__ void __launch_bounds__(BLOCK)
finalize_kernel(const float4* __restrict__ part,
                float* __restrict__ out) {
    float a = 0.f, b = 0.f, c = 0.f, d4 = 0.f;
    for (int i = threadIdx.x; i < NBLOCKS; i += BLOCK) {
        float4 p = part[i];
        a += p.x; b += p.y; c += p.z; d4 += p.w;
    }
    #pragma unroll
    for (int off = 32; off > 0; off >>= 1) {
        a  += __shfl_down(a,  off);
        b  += __shfl_down(b,  off);
        c  += __shfl_down(c,  off);
        d4 += __shfl_down(d4, off);
    }
    __shared__ float lds[4][4];
    int lane = threadIdx.x & 63;
    int wave = threadIdx.x >> 6;
    if (lane == 0) {
        lds[wave][0] = a; lds[wave][1] = b; lds[wave][2] = c; lds[wave][3] = d4;
    }
    __syncthreads();
    if (threadIdx.x == 0) {
        float sim_sum = 0.f, disim_sum = 0.f, n_sim = 0.f, n_disim = 0.f;
        #pragma unroll
        for (int w = 0; w < 4; ++w) {
            sim_sum   += lds[w][0];
            disim_sum += lds[w][1];
            n_sim     += lds[w][2];
            n_disim   += lds[w][3];
        }
        float total = n_sim + n_disim;
        out[0] = (sim_sum * (n_disim / total) +
                  disim_sum * (n_sim / total)) / total;
    }
}

extern "C" void kernel_launch(void* const* d_in, const int* in_sizes, int n_in,
                              void* d_out, int out_size, void* d_ws, size_t ws_size,
                              hipStream_t stream) {
    const int*   edges  = (const int*)d_in[0];    // (N_EDGES, 2) int32
    const float* probas = (const float*)d_in[1];  // (N_NODES,)
    const float* feats  = (const float*)d_in[2];  // (N_NODES, 64)
    float4* part = (float4*)d_ws;                 // NBLOCKS * 16 B = 32 KB

    edge_loss_kernel<<<NBLOCKS, BLOCK, 0, stream>>>(
        (const int2*)edges, probas, (const float4*)feats, part);

    finalize_kernel<<<1, BLOCK, 0, stream>>>(part, (float*)d_out);
}

// Round 5
// 99.657 us; speedup vs baseline: 3.3574x; 1.0742x over previous
//
#include <hip/hip_runtime.h>
#include <math.h>

#define N_EDGES   1000000
#define THR_LO    0.6f
#define THR_HI    0.8f
#define LOG_CLAMP -100.0f

#define NBLOCKS   2048
#define BLOCK     256

// d_ws: float4 part[NBLOCKS] (x=sim_sum, y=disim_sum, z=n_sim, w=n_disim)
// Every block writes its slot unconditionally -> no zero-init needed.

__device__ __forceinline__ void accum_edge(float s, int simflag,
                                           float& sim, float& dis) {
    float d = sqrtf(s);
    if (simflag) {
        sim += fminf(d, 100.0f);            // -max(log(exp(-d)),-100)
    } else {
        float p = expf(-d);
        dis += -fmaxf(log1pf(-p), LOG_CLAMP);
    }
}

__global__ void __launch_bounds__(BLOCK)
edge_loss_kernel(const int2* __restrict__ edges,
                 const float* __restrict__ probas,
                 const float4* __restrict__ feats,   // [N_NODES][16] float4
                 float4* __restrict__ part) {
    const int lane = threadIdx.x & 63;
    const int wave = threadIdx.x >> 6;
    const int grp  = lane >> 2;          // 16 groups of 4 lanes
    const int sub  = lane & 3;

    __shared__ int sh_i[4][64];          // wave-private compacted edges
    __shared__ int sh_j[4][64];

    float sim = 0.f, dis = 0.f, ns = 0.f, nd = 0.f;

    const int gstride = gridDim.x * blockDim.x;
    for (int base = blockIdx.x * blockDim.x; base < N_EDGES; base += gstride) {
        // ---- mask phase: 1 edge per lane (coalesced) ----
        int e = base + threadIdx.x;
        bool in = (e < N_EDGES);
        int2 ij = in ? edges[e] : make_int2(0, 0);
        float pi = probas[ij.x];
        float pj = probas[ij.y];
        bool msim = in & (pi >= THR_HI) & (pj >= THR_HI);
        bool mdis = in & (((pi >= THR_HI) & (pj < THR_LO)) |
                          ((pj >= THR_HI) & (pi < THR_LO)));

        unsigned long long balsim = __ballot(msim);
        unsigned long long baldis = __ballot(mdis);
        unsigned long long m      = balsim | baldis;   // mutually exclusive
        if (lane == 0) {
            ns += (float)__popcll(balsim);
            nd += (float)__popcll(baldis);
        }
        int count = __popcll(m);

        if (msim | mdis) {
            int prefix = __popcll(m & ((1ULL << lane) - 1ULL));
            sh_i[wave][prefix] = ij.x | (msim ? (int)0x80000000 : 0);
            sh_j[wave][prefix] = ij.y;
        }
        __syncthreads();   // LDS write->read ordering (uniform across block)

        // ---- cooperative phase: 4 lanes per edge, 2 edges deep ----
        for (int t = grp; t < count; t += 32) {
            bool h2 = (t + 16) < count;
            int  tb = h2 ? t + 16 : t;

            int xa_i = sh_i[wave][t],  xa_j = sh_j[wave][t];
            int xb_i = sh_i[wave][tb], xb_j = sh_j[wave][tb];

            const float4* rai = feats + (size_t)(xa_i & 0x7FFFFFFF) * 16;
            const float4* raj = feats + (size_t)xa_j * 16;
            const float4* rbi = feats + (size_t)(xb_i & 0x7FFFFFFF) * 16;
            const float4* rbj = feats + (size_t)xb_j * 16;

            // 16 independent 16B loads; each 4-lane group covers 64B lines
            float4 A0 = rai[sub], A1 = rai[sub + 4], A2 = rai[sub + 8], A3 = rai[sub + 12];
            float4 B0 = raj[sub], B1 = raj[sub + 4], B2 = raj[sub + 8], B3 = raj[sub + 12];
            float4 C0 = rbi[sub], C1 = rbi[sub + 4], C2 = rbi[sub + 8], C3 = rbi[sub + 12];
            float4 D0 = rbj[sub], D1 = rbj[sub + 4], D2 = rbj[sub + 8], D3 = rbj[sub + 12];

            float s1 = 0.f, s2 = 0.f, dx, dy, dz, dw;
            dx = A0.x-B0.x; dy = A0.y-B0.y; dz = A0.z-B0.z; dw = A0.w-B0.w;
            s1 += dx*dx + dy*dy + dz*dz + dw*dw;
            dx = A1.x-B1.x; dy = A1.y-B1.y; dz = A1.z-B1.z; dw = A1.w-B1.w;
            s1 += dx*dx + dy*dy + dz*dz + dw*dw;
            dx = A2.x-B2.x; dy = A2.y-B2.y; dz = A2.z-B2.z; dw = A2.w-B2.w;
            s1 += dx*dx + dy*dy + dz*dz + dw*dw;
            dx = A3.x-B3.x; dy = A3.y-B3.y; dz = A3.z-B3.z; dw = A3.w-B3.w;
            s1 += dx*dx + dy*dy + dz*dz + dw*dw;

            dx = C0.x-D0.x; dy = C0.y-D0.y; dz = C0.z-D0.z; dw = C0.w-D0.w;
            s2 += dx*dx + dy*dy + dz*dz + dw*dw;
            dx = C1.x-D1.x; dy = C1.y-D1.y; dz = C1.z-D1.z; dw = C1.w-D1.w;
            s2 += dx*dx + dy*dy + dz*dz + dw*dw;
            dx = C2.x-D2.x; dy = C2.y-D2.y; dz = C2.z-D2.z; dw = C2.w-D2.w;
            s2 += dx*dx + dy*dy + dz*dz + dw*dw;
            dx = C3.x-D3.x; dy = C3.y-D3.y; dz = C3.z-D3.z; dw = C3.w-D3.w;
            s2 += dx*dx + dy*dy + dz*dz + dw*dw;

            s1 += __shfl_xor(s1, 1); s1 += __shfl_xor(s1, 2);
            s2 += __shfl_xor(s2, 1); s2 += __shfl_xor(s2, 2);

            if (sub == 0) {
                accum_edge(s1, ((unsigned)xa_i) >> 31, sim, dis);
                if (h2) accum_edge(s2, ((unsigned)xb_i) >> 31, sim, dis);
            }
        }
        __syncthreads();   // protect sh_* before next iteration's writes
    }

    // ---- block reduction (no global atomics) ----
    #pragma unroll
    for (int off = 32; off > 0; off >>= 1) {
        sim += __shfl_down(sim, off);
        dis += __shfl_down(dis, off);
        ns  += __shfl_down(ns,  off);
        nd  += __shfl_down(nd,  off);
    }
    __shared__ float lds[4][4];
    if (lane == 0) {
        lds[wave][0] = sim; lds[wave][1] = dis;
        lds[wave][2] = ns;  lds[wave][3] = nd;
    }
    __syncthreads();
    if (threadIdx.x == 0) {
        float a = 0.f, b = 0.f, c = 0.f, d4 = 0.f;
        #pragma unroll
        for (int w = 0; w < 4; ++w) {
            a += lds[w][0]; b += lds[w][1]; c += lds[w][2]; d4 += lds[w][3];
        }
        part[blockIdx.x] = make_float4(a, b, c, d4);
    }
}

__global__ void __launch_bounds__(BLOCK)
finalize_kernel(const float4* __restrict__ part,
                float* __restrict__ out) {
    float a = 0.f, b = 0.f, c = 0.f, d4 = 0.f;
    for (int i = threadIdx.x; i < NBLOCKS; i += BLOCK) {
        float4 p = part[i];
        a += p.x; b += p.y; c += p.z; d4 += p.w;
    }
    #pragma unroll
    for (int off = 32; off > 0; off >>= 1) {
        a  += __shfl_down(a,  off);
        b  += __shfl_down(b,  off);
        c  += __shfl_down(c,  off);
        d4 += __shfl_down(d4, off);
    }
    __shared__ float lds[4][4];
    int lane = threadIdx.x & 63;
    int wave = threadIdx.x >> 6;
    if (lane == 0) {
        lds[wave][0] = a; lds[wave][1] = b; lds[wave][2] = c; lds[wave][3] = d4;
    }
    __syncthreads();
    if (threadIdx.x == 0) {
        float sim_sum = 0.f, disim_sum = 0.f, n_sim = 0.f, n_disim = 0.f;
        #pragma unroll
        for (int w = 0; w < 4; ++w) {
            sim_sum   += lds[w][0];
            disim_sum += lds[w][1];
            n_sim     += lds[w][2];
            n_disim   += lds[w][3];
        }
        float total = n_sim + n_disim;
        out[0] = (sim_sum * (n_disim / total) +
                  disim_sum * (n_sim / total)) / total;
    }
}

extern "C" void kernel_launch(void* const* d_in, const int* in_sizes, int n_in,
                              void* d_out, int out_size, void* d_ws, size_t ws_size,
                              hipStream_t stream) {
    const int*   edges  = (const int*)d_in[0];    // (N_EDGES, 2) int32
    const float* probas = (const float*)d_in[1];  // (N_NODES,)
    const float* feats  = (const float*)d_in[2];  // (N_NODES, 64)
    float4* part = (float4*)d_ws;                 // NBLOCKS * 16 B = 32 KB

    edge_loss_kernel<<<NBLOCKS, BLOCK, 0, stream>>>(
        (const int2*)edges, probas, (const float4*)feats, part);

    finalize_kernel<<<1, BLOCK, 0, stream>>>(part, (float*)d_out);
}

// Round 6
// 94.901 us; speedup vs baseline: 3.5257x; 1.0501x over previous
//
#include <hip/hip_runtime.h>
#include <math.h>

#define N_EDGES   1000000
#define N_NODES   100000
#define THR_LO    0.6f
#define THR_HI    0.8f
#define LOG_CLAMP -100.0f

#define NBLOCKS   2048
#define BLOCK     256

// d_ws layout:
//   0x00000: float4 part[NBLOCKS]      32 KB  (block partials; written unconditionally)
//   0x08000: uint   cls[N_NODES/16]    25 KB  (2-bit node codes, 16 per word)
//   0x10000: ushort bfeats[N_NODES*64] 12.8 MB (bf16 feats, row = 128 B)
#define CLS_OFF   0x8000
#define BF_OFF    0x10000

__device__ __forceinline__ unsigned short f2bf(float f) {
    unsigned b = __float_as_uint(f);
    b += 0x7FFFu + ((b >> 16) & 1u);          // round-to-nearest-even
    return (unsigned short)(b >> 16);
}

// ---------------- prep: bf16 convert + 2-bit classify ----------------
__global__ void __launch_bounds__(BLOCK)
prep_kernel(const float* __restrict__ probas,
            const float4* __restrict__ feats,     // N_NODES*16 float4
            unsigned* __restrict__ cls,
            ushort4* __restrict__ bf) {           // N_NODES*16 ushort4
    int t = blockIdx.x * blockDim.x + threadIdx.x;
    const int NF4 = N_NODES * 16;
    if (t < NF4) {
        float4 v = feats[t];
        bf[t] = make_ushort4(f2bf(v.x), f2bf(v.y), f2bf(v.z), f2bf(v.w));
    }
    if (t < N_NODES / 16) {                       // 6250 words, 16 nodes each
        unsigned w = 0;
        #pragma unroll
        for (int k = 0; k < 16; ++k) {
            float p = probas[t * 16 + k];
            unsigned c = (p >= THR_HI ? 1u : 0u) | (p < THR_LO ? 2u : 0u);
            w |= c << (2 * k);
        }
        cls[t] = w;
    }
}

// ---------------- bf16 diff-square helpers ----------------
__device__ __forceinline__ float bfsq(unsigned a, unsigned b) {
    float alo = __uint_as_float(a << 16);
    float ahi = __uint_as_float(a & 0xFFFF0000u);
    float blo = __uint_as_float(b << 16);
    float bhi = __uint_as_float(b & 0xFFFF0000u);
    float d1 = alo - blo, d2 = ahi - bhi;
    return d1 * d1 + d2 * d2;
}
__device__ __forceinline__ float bfsq16(uint4 a0, uint4 b0, uint4 a1, uint4 b1) {
    return bfsq(a0.x, b0.x) + bfsq(a0.y, b0.y) + bfsq(a0.z, b0.z) + bfsq(a0.w, b0.w)
         + bfsq(a1.x, b1.x) + bfsq(a1.y, b1.y) + bfsq(a1.z, b1.z) + bfsq(a1.w, b1.w);
}

__device__ __forceinline__ void accum_edge(float s, int simflag,
                                           float& sim, float& dis) {
    float d = sqrtf(s);
    if (simflag) {
        sim += fminf(d, 100.0f);                  // -max(log(exp(-d)),-100)
    } else {
        float p = expf(-d);
        dis += -fmaxf(log1pf(-p), LOG_CLAMP);
    }
}

// ---------------- main: mask + compact + coalesced bf16 gathers ----------------
__global__ void __launch_bounds__(BLOCK)
edge_loss_kernel(const int2* __restrict__ edges,
                 const unsigned* __restrict__ cls,
                 const uint4* __restrict__ bfeat,   // N_NODES rows of 8 uint4
                 float4* __restrict__ part) {
    const int lane = threadIdx.x & 63;
    const int wave = threadIdx.x >> 6;
    const int grp  = lane >> 2;                    // 16 groups of 4 lanes
    const int sub  = lane & 3;

    __shared__ int sh_i[4][64];
    __shared__ int sh_j[4][64];

    float sim = 0.f, dis = 0.f, ns = 0.f, nd = 0.f;

    const int gstride = gridDim.x * blockDim.x;
    for (int base = blockIdx.x * blockDim.x; base < N_EDGES; base += gstride) {
        // ---- mask phase: 1 edge per lane, class codes from 25 KB L1-resident table
        int e = base + threadIdx.x;
        bool in = (e < N_EDGES);
        int2 ij = in ? edges[e] : make_int2(0, 0);
        unsigned ci = (cls[ij.x >> 4] >> ((ij.x & 15) * 2)) & 3u;
        unsigned cj = (cls[ij.y >> 4] >> ((ij.y & 15) * 2)) & 3u;
        bool msim = in && ((ci & cj & 1u) != 0u);
        bool mdis = in && ((((ci & 1u) & (cj >> 1)) | ((cj & 1u) & (ci >> 1))) != 0u);

        unsigned long long balsim = __ballot(msim);
        unsigned long long baldis = __ballot(mdis);
        unsigned long long m      = balsim | baldis;
        if (lane == 0) {
            ns += (float)__popcll(balsim);
            nd += (float)__popcll(baldis);
        }
        int count = __popcll(m);

        if (msim | mdis) {
            int prefix = __popcll(m & ((1ULL << lane) - 1ULL));
            sh_i[wave][prefix] = ij.x | (msim ? (int)0x80000000 : 0);
            sh_j[wave][prefix] = ij.y;
        }
        __syncthreads();

        // ---- cooperative phase: 4 lanes/edge, 2 edges deep, bf16 rows (128 B)
        for (int t = grp; t < count; t += 32) {
            bool h2 = (t + 16) < count;
            int  tb = h2 ? t + 16 : t;

            int xa_i = sh_i[wave][t],  xa_j = sh_j[wave][t];
            int xb_i = sh_i[wave][tb], xb_j = sh_j[wave][tb];

            const uint4* rai = bfeat + (size_t)(xa_i & 0x7FFFFFFF) * 8;
            const uint4* raj = bfeat + (size_t)xa_j * 8;
            const uint4* rbi = bfeat + (size_t)(xb_i & 0x7FFFFFFF) * 8;
            const uint4* rbj = bfeat + (size_t)xb_j * 8;

            // 8 independent 16B loads in flight per lane
            uint4 A0 = rai[sub], A1 = rai[sub + 4];
            uint4 B0 = raj[sub], B1 = raj[sub + 4];
            uint4 C0 = rbi[sub], C1 = rbi[sub + 4];
            uint4 D0 = rbj[sub], D1 = rbj[sub + 4];

            float s1 = bfsq16(A0, B0, A1, B1);
            float s2 = bfsq16(C0, D0, C1, D1);

            s1 += __shfl_xor(s1, 1); s1 += __shfl_xor(s1, 2);
            s2 += __shfl_xor(s2, 1); s2 += __shfl_xor(s2, 2);

            if (sub == 0) {
                accum_edge(s1, ((unsigned)xa_i) >> 31, sim, dis);
                if (h2) accum_edge(s2, ((unsigned)xb_i) >> 31, sim, dis);
            }
        }
        __syncthreads();
    }

    // ---- block reduction (plain store, no global atomics) ----
    #pragma unroll
    for (int off = 32; off > 0; off >>= 1) {
        sim += __shfl_down(sim, off);
        dis += __shfl_down(dis, off);
        ns  += __shfl_down(ns,  off);
        nd  += __shfl_down(nd,  off);
    }
    __shared__ float lds[4][4];
    if (lane == 0) {
        lds[wave][0] = sim; lds[wave][1] = dis;
        lds[wave][2] = ns;  lds[wave][3] = nd;
    }
    __syncthreads();
    if (threadIdx.x == 0) {
        float a = 0.f, b = 0.f, c = 0.f, d4 = 0.f;
        #pragma unroll
        for (int w = 0; w < 4; ++w) {
            a += lds[w][0]; b += lds[w][1]; c += lds[w][2]; d4 += lds[w][3];
        }
        part[blockIdx.x] = make_float4(a, b, c, d4);
    }
}

__global__ void __launch_bounds__(BLOCK)
finalize_kernel(const float4* __restrict__ part,
                float* __restrict__ out) {
    float a = 0.f, b = 0.f, c = 0.f, d4 = 0.f;
    for (int i = threadIdx.x; i < NBLOCKS; i += BLOCK) {
        float4 p = part[i];
        a += p.x; b += p.y; c += p.z; d4 += p.w;
    }
    #pragma unroll
    for (int off = 32; off > 0; off >>= 1) {
        a  += __shfl_down(a,  off);
        b  += __shfl_down(b,  off);
        c  += __shfl_down(c,  off);
        d4 += __shfl_down(d4, off);
    }
    __shared__ float lds[4][4];
    int lane = threadIdx.x & 63;
    int wave = threadIdx.x >> 6;
    if (lane == 0) {
        lds[wave][0] = a; lds[wave][1] = b; lds[wave][2] = c; lds[wave][3] = d4;
    }
    __syncthreads();
    if (threadIdx.x == 0) {
        float sim_sum = 0.f, disim_sum = 0.f, n_sim = 0.f, n_disim = 0.f;
        #pragma unroll
        for (int w = 0; w < 4; ++w) {
            sim_sum   += lds[w][0];
            disim_sum += lds[w][1];
            n_sim     += lds[w][2];
            n_disim   += lds[w][3];
        }
        float total = n_sim + n_disim;
        out[0] = (sim_sum * (n_disim / total) +
                  disim_sum * (n_sim / total)) / total;
    }
}

extern "C" void kernel_launch(void* const* d_in, const int* in_sizes, int n_in,
                              void* d_out, int out_size, void* d_ws, size_t ws_size,
                              hipStream_t stream) {
    const int*   edges  = (const int*)d_in[0];    // (N_EDGES, 2) int32
    const float* probas = (const float*)d_in[1];  // (N_NODES,)
    const float* feats  = (const float*)d_in[2];  // (N_NODES, 64) fp32

    float4*   part = (float4*)d_ws;
    unsigned* cls  = (unsigned*)((char*)d_ws + CLS_OFF);
    ushort4*  bf   = (ushort4*)((char*)d_ws + BF_OFF);

    // prep: 1.6M float4 conversions + 6250 class words
    const int NF4 = N_NODES * 16;
    prep_kernel<<<(NF4 + BLOCK - 1) / BLOCK, BLOCK, 0, stream>>>(
        probas, (const float4*)feats, cls, bf);

    edge_loss_kernel<<<NBLOCKS, BLOCK, 0, stream>>>(
        (const int2*)edges, cls, (const uint4*)bf, part);

    finalize_kernel<<<1, BLOCK, 0, stream>>>(part, (float*)d_out);
}